// Round 6
// baseline (477.323 us; speedup 1.0000x reference)
//
#include <hip/hip_runtime.h>
#include <hip/hip_cooperative_groups.h>
#include <math.h>

namespace cg = cooperative_groups;

#define DIM 128
// ws float layout:
//   W[i] f32, i=1..63 : (i-1)*16384          (W_i = E^i)
//   G ping-pong s=0,1 : (63+s)*16384         (E64 -> s0)
//   Y[j] f32, j=0..63 : YOFFI + j*8192
//   X^q  (q=1..8)     : XOFF(q-1)
//   T_i  (i=1..64)    : TOFF(i)              (Horner intermediate)
//   Wf f16 frags      : float idx FWOFFI
//   Yf f16 frags      : float idx FYOFFI
#define WOFFI(i) (((i) - 1) * 16384)
#define GOFFI(s) ((63 + (s)) * 16384)
#define YOFFI    (65 * 16384)
#define XOFF(q)  ((97 + (q)) * 16384)
#define TOFF(i)  ((105 + (i) - 1) * 16384)
#define FWOFFI   (169 * 16384)
#define FYOFFI   (201 * 16384)

typedef _Float16 f16x8 __attribute__((ext_vector_type(8)));
typedef float    f32x4 __attribute__((ext_vector_type(4)));

__device__ __forceinline__ float4 ld4(const float* p) { return *(const float4*)p; }

// ---- LDS-tiled 128x(32-panel) matmul pieces -------------------------------
__device__ __forceinline__ void stageA(const float* __restrict__ A, float* AT, int tid)
{
    for (int idx = tid; idx < DIM * DIM; idx += 256)
        AT[(idx & 127) * 132 + (idx >> 7)] = A[idx];      // AT[k][d] = A[d][k]
}

__device__ __forceinline__ void mm_core(const float* AT, const float* Bs,
                                        float (&acc)[4][4], int tid)
{
    int td = tid & 31, tc = tid >> 5;
    int d0 = td * 4, c0 = tc * 4;
    #pragma unroll 4
    for (int k = 0; k < DIM; k++) {
        float4 a4 = ld4(&AT[k * 132 + d0]);
        float4 b4 = ld4(&Bs[k * 36 + c0]);
        float a_[4] = {a4.x, a4.y, a4.z, a4.w};
        float b_[4] = {b4.x, b4.y, b4.z, b4.w};
        #pragma unroll
        for (int i = 0; i < 4; i++)
            #pragma unroll
            for (int j = 0; j < 4; j++) acc[i][j] += a_[i] * b_[j];
    }
}

__device__ __forceinline__ void mm_plain(const float* __restrict__ A,
                                         const float* __restrict__ B,
                                         float* __restrict__ C,
                                         int ncols, int cpan,
                                         float* AT, float* Bs, int tid)
{
    stageA(A, AT, tid);
    for (int idx = tid; idx < DIM * 32; idx += 256) {
        int k = idx >> 5, cc = idx & 31;
        Bs[k * 36 + cc] = B[(size_t)k * ncols + cpan + cc];
    }
    __syncthreads();
    float acc[4][4] = {};
    mm_core(AT, Bs, acc, tid);
    int td = tid & 31, tc = tid >> 5;
    int d0 = td * 4, c0 = tc * 4;
    #pragma unroll
    for (int i = 0; i < 4; i++) {
        float4 st = make_float4(acc[i][0], acc[i][1], acc[i][2], acc[i][3]);
        *(float4*)&C[(size_t)(d0 + i) * ncols + cpan + c0] = st;
    }
}

// ---- the whole chain as ONE cooperative kernel ----------------------------
__global__ __launch_bounds__(256) void k_chain(const float* __restrict__ t,
                                               const float* __restrict__ x0,
                                               const float* __restrict__ S,
                                               const float* __restrict__ D,
                                               float* __restrict__ ws)
{
    __shared__ __align__(16) float AT[DIM * 132];
    __shared__ __align__(16) float Bs[DIM * 36];
    cg::grid_group grid = cg::this_grid();
    const int tid = threadIdx.x, bid = blockIdx.x;

    // P0: X = A*dt ; Y0 = x0
    {
        float dt = t[1] - t[0];
        int e = bid * 256 + tid;
        if (e < 16384) {
            int r = e >> 7, c = e & 127;
            float a;
            if (r == c)      a = -log1pf(expf(D[r]));
            else if (r < c)  a =  S[(r * (2 * DIM - r - 1)) / 2 + (c - r - 1)];
            else             a = -S[(c * (2 * DIM - c - 1)) / 2 + (r - c - 1)];
            ws[XOFF(0) + e] = a * dt;
        } else if (e < 16384 + 8192) {
            ws[YOFFI + (e - 16384)] = x0[e - 16384];
        }
    }
    grid.sync();

    // P1: X2 = X*X
    if (bid < 4) mm_plain(ws + XOFF(0), ws + XOFF(0), ws + XOFF(1), 128, (bid & 3) * 32, AT, Bs, tid);
    grid.sync();

    // P2: X3 = X2*X ; X4 = X2*X2
    if (bid < 8) {
        int job = bid >> 2, pan = (bid & 3) * 32;
        mm_plain(ws + XOFF(1), ws + XOFF(job), ws + XOFF(2 + job), 128, pan, AT, Bs, tid);
    }
    grid.sync();

    // P3: X5..X8 = X4 * X1..X4
    if (bid < 16) {
        int job = bid >> 2, pan = (bid & 3) * 32;
        mm_plain(ws + XOFF(3), ws + XOFF(job), ws + XOFF(4 + job), 128, pan, AT, Bs, tid);
    }
    grid.sync();

    // P4: T_i = X8 @ P2(i) + P1(i)   for i = 1..64   (256 WGs, full chip)
    // P_m(i) = sum_{q=0..7} c_{8m+q}(i) X^q,  c_n(i) = i^n/n!
    {
        int i = (bid >> 2) + 1;
        int cpan = (bid & 3) * 32;
        float c[24]; c[0] = 1.0f;
        #pragma unroll
        for (int n = 1; n < 24; n++) c[n] = c[n - 1] * ((float)i / (float)n);
        stageA(ws + XOFF(7), AT, tid);
        for (int idx = tid; idx < DIM * 32; idx += 256) {
            int k = idx >> 5, cc = idx & 31, col = cpan + cc;
            size_t e = (size_t)k * DIM + col;
            float b = (k == col) ? c[16] : 0.0f;
            #pragma unroll
            for (int q = 1; q < 8; q++) b += c[16 + q] * ws[XOFF(q - 1) + e];
            Bs[k * 36 + cc] = b;
        }
        __syncthreads();
        float acc[4][4] = {};
        mm_core(AT, Bs, acc, tid);
        int td = tid & 31, tc = tid >> 5, d0 = td * 4, c0 = tc * 4;
        float* T = ws + TOFF(i);
        #pragma unroll
        for (int r = 0; r < 4; r++) {
            int dd = d0 + r;
            #pragma unroll
            for (int j = 0; j < 4; j++) {
                int col = cpan + c0 + j;
                size_t e = (size_t)dd * DIM + col;
                float add = (dd == col) ? c[8] : 0.0f;
                #pragma unroll
                for (int q = 1; q < 8; q++) add += c[8 + q] * ws[XOFF(q - 1) + e];
                acc[r][j] += add;
            }
            float4 st = make_float4(acc[r][0], acc[r][1], acc[r][2], acc[r][3]);
            *(float4*)&T[(size_t)dd * DIM + cpan + c0] = st;
        }
    }
    grid.sync();

    // P5: E^i = X8 @ T_i + P0(i) ;  i<=63 -> W_i, i==64 -> G0
    {
        int i = (bid >> 2) + 1;
        int cpan = (bid & 3) * 32;
        float c[8]; c[0] = 1.0f;
        #pragma unroll
        for (int n = 1; n < 8; n++) c[n] = c[n - 1] * ((float)i / (float)n);
        stageA(ws + XOFF(7), AT, tid);
        const float* T = ws + TOFF(i);
        for (int idx = tid; idx < DIM * 32; idx += 256) {
            int k = idx >> 5, cc = idx & 31;
            Bs[k * 36 + cc] = T[(size_t)k * DIM + cpan + cc];
        }
        __syncthreads();
        float acc[4][4] = {};
        mm_core(AT, Bs, acc, tid);
        int td = tid & 31, tc = tid >> 5, d0 = td * 4, c0 = tc * 4;
        float* W = (i < 64) ? (ws + WOFFI(i)) : (ws + GOFFI(0));
        #pragma unroll
        for (int r = 0; r < 4; r++) {
            int dd = d0 + r;
            #pragma unroll
            for (int j = 0; j < 4; j++) {
                int col = cpan + c0 + j;
                size_t e = (size_t)dd * DIM + col;
                float add = (dd == col) ? 1.0f : 0.0f;
                #pragma unroll
                for (int q = 1; q < 8; q++) add += c[q] * ws[XOFF(q - 1) + e];
                acc[r][j] += add;
            }
            float4 st = make_float4(acc[r][0], acc[r][1], acc[r][2], acc[r][3]);
            *(float4*)&W[(size_t)dd * DIM + cpan + c0] = st;
        }
    }
    grid.sync();

    // P6..P11: Y doubling, G squarings ride along.
    // level d: read G at slot (d&1); squaring writes slot !(d&1) (skip d=5);
    //          Y_{2^d + j} = G * Y_j  (j < 2^d, ncols=64 -> 2 panels)
    for (int d = 0; d < 6; d++) {
        const float* G = ws + GOFFI(d & 1);
        if (bid < 4) {
            if (d < 5)
                mm_plain(G, G, ws + GOFFI(1 - (d & 1)), 128, (bid & 3) * 32, AT, Bs, tid);
        } else {
            int b2 = bid - 4;
            int j = b2 >> 1, pan = (b2 & 1) * 32;
            if (j < (1 << d))
                mm_plain(G, ws + YOFFI + (size_t)j * 8192,
                         ws + YOFFI + (size_t)((1 << d) + j) * 8192, 64, pan, AT, Bs, tid);
        }
        grid.sync();
    }

    // P12: convert W_0..63, Y_0..63 to f16 fragment tables (grid-stride)
    {
        _Float16* Wf = (_Float16*)(ws + FWOFFI);
        _Float16* Yf = (_Float16*)(ws + FYOFFI);
        for (int g = bid * 256 + tid; g < 196608; g += 65536) {
            if (g < 131072) {                       // W: 64 mats x 2048 chunks
                int i = g >> 11, c = g & 2047;
                int m = c >> 4, k0 = (c & 15) << 3;
                float v[8];
                if (i == 0) {
                    #pragma unroll
                    for (int q = 0; q < 8; q++) v[q] = (m == k0 + q) ? 1.0f : 0.0f;
                } else {
                    const float* src = ws + WOFFI(i) + (size_t)m * DIM + k0;
                    float4 a = ld4(src), b = ld4(src + 4);
                    v[0]=a.x; v[1]=a.y; v[2]=a.z; v[3]=a.w; v[4]=b.x; v[5]=b.y; v[6]=b.z; v[7]=b.w;
                }
                f16x8 hv;
                #pragma unroll
                for (int q = 0; q < 8; q++) hv[q] = (_Float16)v[q];
                int lane = (m & 15) | (((k0 >> 3) & 3) << 4);
                size_t off = (size_t)i * 16384 + (((size_t)(m >> 4) * 4 + (k0 >> 5)) * 64 + lane) * 8;
                *(f16x8*)(Wf + off) = hv;
            } else {                                 // Y: 64 mats x 1024 chunks
                int g2 = g - 131072;
                int j = g2 >> 10, c = g2 & 1023;
                int n = c >> 4, k0 = (c & 15) << 3;
                const float* src = ws + YOFFI + (size_t)j * 8192 + n;
                f16x8 hv;
                #pragma unroll
                for (int q = 0; q < 8; q++) hv[q] = (_Float16)src[(size_t)(k0 + q) * 64];
                int lane = (n & 15) | (((k0 >> 3) & 3) << 4);
                size_t off = (size_t)j * 8192 + (((size_t)(n >> 4) * 4 + (k0 >> 5)) * 64 + lane) * 8;
                *(f16x8*)(Yf + off) = hv;
            }
        }
    }
}

// ---- final: out[64j+i] = W_i @ Y_j via MFMA (batch-major stores) ----------
__global__ __launch_bounds__(256) void k_final(const _Float16* __restrict__ Wf,
                                               const _Float16* __restrict__ Yf,
                                               float* __restrict__ out)
{
    int i = blockIdx.x, j = blockIdx.y;
    int tid = threadIdx.x, wave = tid >> 6, lane = tid & 63;
    const _Float16* Ab = Yf + (size_t)j * 8192;
    const _Float16* Bb = Wf + (size_t)i * 16384;
    f32x4 acc[4][2] = {};
    #pragma unroll
    for (int ks = 0; ks < 4; ks++) {
        f16x8 a[4], b[2];
        #pragma unroll
        for (int bt = 0; bt < 4; bt++)
            a[bt] = *(const f16x8*)(Ab + (((size_t)bt * 4 + ks) * 64 + lane) * 8);
        #pragma unroll
        for (int nn = 0; nn < 2; nn++)
            b[nn] = *(const f16x8*)(Bb + (((size_t)(wave * 2 + nn) * 4 + ks) * 64 + lane) * 8);
        #pragma unroll
        for (int bt = 0; bt < 4; bt++)
            #pragma unroll
            for (int nn = 0; nn < 2; nn++)
                acc[bt][nn] = __builtin_amdgcn_mfma_f32_16x16x32_f16(a[bt], b[nn], acc[bt][nn], 0, 0, 0);
    }
    float* slab = out + (size_t)(j * 64 + i) * 8192;
    int nlo = lane & 15, b0 = (lane >> 4) * 4;
    #pragma unroll
    for (int bt = 0; bt < 4; bt++)
        #pragma unroll
        for (int nn = 0; nn < 2; nn++) {
            int n = (wave * 2 + nn) * 16 + nlo;
            __builtin_nontemporal_store(acc[bt][nn],
                (f32x4*)&slab[(size_t)n * 64 + bt * 16 + b0]);
        }
}

extern "C" void kernel_launch(void* const* d_in, const int* in_sizes, int n_in,
                              void* d_out, int out_size, void* d_ws, size_t ws_size,
                              hipStream_t stream)
{
    const float* t  = (const float*)d_in[0];
    const float* x0 = (const float*)d_in[1];
    const float* S  = (const float*)d_in[2];
    const float* D  = (const float*)d_in[3];
    float* out = (float*)d_out;
    float* ws  = (float*)d_ws;
    _Float16* Wf = (_Float16*)(ws + FWOFFI);
    _Float16* Yf = (_Float16*)(ws + FYOFFI);

    void* args[] = {(void*)&t, (void*)&x0, (void*)&S, (void*)&D, (void*)&ws};
    hipLaunchCooperativeKernel((const void*)k_chain, dim3(256), dim3(256), args, 0, stream);

    hipLaunchKernelGGL(k_final, dim3(64, 64), dim3(256), 0, stream, Wf, Yf, out);
}

// Round 7
// 380.559 us; speedup vs baseline: 1.2543x; 1.2543x over previous
//
#include <hip/hip_runtime.h>
#include <math.h>

#define DIM 128
// ws float layout:
//   G^(2^s) f32, s=0..5 : GP(s) = s*16384        (GP(0) = E^64, from k_ps2)
//   Y[j] f32, j=0..63   : YOFFI + j*8192
//   X^q  (q=1..8)       : XOFF(q-1) = (97+q-1)*16384
//   T_i  (i=1..64)      : TOFF(i)  = (105+i-1)*16384
//   Wf f16 frags        : float idx FWOFFI (64 mats x 16384 halves)
//   Yf f16 frags        : float idx FYOFFI (64 mats x 8192 halves)
#define GP(s)    ((s) * 16384)
#define YOFFI    (65 * 16384)
#define XOFF(q)  ((97 + (q)) * 16384)
#define TOFF(i)  ((105 + (i) - 1) * 16384)
#define FWOFFI   (169 * 16384)
#define FYOFFI   (201 * 16384)

typedef _Float16 f16x8 __attribute__((ext_vector_type(8)));
typedef float    f32x4 __attribute__((ext_vector_type(4)));

__device__ __forceinline__ float4 ld4(const float* p) { return *(const float4*)p; }

// stage A transposed into AT[k][d] (= A[d][k]), 256-thread version
__device__ __forceinline__ void stageA(const float* __restrict__ A, float* AT, int tid)
{
    for (int idx = tid; idx < DIM * DIM; idx += 256)
        AT[(idx & 127) * 132 + (idx >> 7)] = A[idx];
}

// 128x32-panel matmul core: acc += A*B over full k, AT[128][132], Bs[128][36]
__device__ __forceinline__ void mm_core(const float* AT, const float* Bs,
                                        float (&acc)[4][4], int tid)
{
    int d0 = (tid & 31) * 4, c0 = (tid >> 5) * 4;
    #pragma unroll 4
    for (int k = 0; k < DIM; k++) {
        float4 a4 = ld4(&AT[k * 132 + d0]);
        float4 b4 = ld4(&Bs[k * 36 + c0]);
        float a_[4] = {a4.x, a4.y, a4.z, a4.w};
        float b_[4] = {b4.x, b4.y, b4.z, b4.w};
        #pragma unroll
        for (int i = 0; i < 4; i++)
            #pragma unroll
            for (int j = 0; j < 4; j++) acc[i][j] += a_[i] * b_[j];
    }
}

// ---- L1: build X, Y0, W0-frags; X^2..X^8 via 7 in-LDS matmuls (1 WG) ------
__global__ __launch_bounds__(1024) void k_xpow(const float* __restrict__ t,
                                               const float* __restrict__ x0,
                                               const float* __restrict__ S,
                                               const float* __restrict__ D,
                                               float* __restrict__ ws)
{
    __shared__ __align__(16) float AT[DIM * 132];   // X transposed (fixed A)
    __shared__ __align__(16) float Bs[DIM * 132];   // X^{n-1}
    int tid = threadIdx.x;
    float dt = t[1] - t[0];
    for (int e = tid; e < 16384; e += 1024) {
        int r = e >> 7, c = e & 127;
        float a;
        if (r == c)      a = -log1pf(expf(D[r]));
        else if (r < c)  a =  S[(r * (2 * DIM - r - 1)) / 2 + (c - r - 1)];
        else             a = -S[(c * (2 * DIM - c - 1)) / 2 + (r - c - 1)];
        a *= dt;
        ws[XOFF(0) + e] = a;
        AT[c * 132 + r] = a;
        Bs[r * 132 + c] = a;
    }
    for (int e = tid; e < 8192; e += 1024) ws[YOFFI + e] = x0[e];
    {   // W0 = I fragments
        _Float16* Wf = (_Float16*)(ws + FWOFFI);
        for (int ch = tid; ch < 2048; ch += 1024) {
            int m = ch >> 4, k0 = (ch & 15) << 3;
            f16x8 hv;
            #pragma unroll
            for (int q = 0; q < 8; q++) hv[q] = (m == k0 + q) ? (_Float16)1.0f : (_Float16)0.0f;
            int lane = (m & 15) | (((k0 >> 3) & 3) << 4);
            size_t off = (((size_t)(m >> 4) * 4 + (k0 >> 5)) * 64 + lane) * 8;
            *(f16x8*)(Wf + off) = hv;
        }
    }
    __syncthreads();
    int d0 = (tid & 31) * 4, c0 = (tid >> 5) * 4;    // 32x32 thread grid -> 128x128
    for (int n = 2; n <= 8; n++) {
        float acc[4][4] = {};
        #pragma unroll 4
        for (int k = 0; k < DIM; k++) {
            float4 a4 = ld4(&AT[k * 132 + d0]);
            float4 b4 = ld4(&Bs[k * 132 + c0]);
            float a_[4] = {a4.x, a4.y, a4.z, a4.w};
            float b_[4] = {b4.x, b4.y, b4.z, b4.w};
            #pragma unroll
            for (int i = 0; i < 4; i++)
                #pragma unroll
                for (int j = 0; j < 4; j++) acc[i][j] += a_[i] * b_[j];
        }
        __syncthreads();
        #pragma unroll
        for (int r = 0; r < 4; r++) {
            float4 st = make_float4(acc[r][0], acc[r][1], acc[r][2], acc[r][3]);
            *(float4*)&ws[XOFF(n - 1) + (size_t)(d0 + r) * DIM + c0] = st;
            #pragma unroll
            for (int j = 0; j < 4; j++) Bs[(d0 + r) * 132 + c0 + j] = acc[r][j];
        }
        __syncthreads();
    }
}

// ---- L2: T_i = X8 @ P2(i) + P1(i), i=1..64 (grid 64x4) --------------------
__global__ __launch_bounds__(256) void k_ps1(float* __restrict__ ws)
{
    __shared__ __align__(16) float AT[DIM * 132];
    __shared__ __align__(16) float Bs[DIM * 36];
    int i = blockIdx.x + 1, cpan = blockIdx.y * 32, tid = threadIdx.x;
    float c[24]; c[0] = 1.0f;
    #pragma unroll
    for (int n = 1; n < 24; n++) c[n] = c[n - 1] * ((float)i / (float)n);
    stageA(ws + XOFF(7), AT, tid);
    for (int idx = tid; idx < DIM * 8; idx += 256) {     // 4 cols per slot
        int k = idx >> 3, cc4 = (idx & 7) * 4;
        float4 b = make_float4(0.f, 0.f, 0.f, 0.f);
        #pragma unroll
        for (int q = 1; q < 8; q++) {
            float4 x = ld4(&ws[XOFF(q - 1) + (size_t)k * DIM + cpan + cc4]);
            b.x += c[16 + q] * x.x; b.y += c[16 + q] * x.y;
            b.z += c[16 + q] * x.z; b.w += c[16 + q] * x.w;
        }
        int col = cpan + cc4;
        if (k >= col && k < col + 4) (&b.x)[k - col] += c[16];
        *(float4*)&Bs[k * 36 + cc4] = b;
    }
    __syncthreads();
    float acc[4][4] = {};
    mm_core(AT, Bs, acc, tid);
    int d0 = (tid & 31) * 4, c0 = (tid >> 5) * 4;
    float* T = ws + TOFF(i);
    #pragma unroll
    for (int r = 0; r < 4; r++) {
        int dd = d0 + r;
        float add[4] = {0.f, 0.f, 0.f, 0.f};
        #pragma unroll
        for (int q = 1; q < 8; q++) {
            float4 x = ld4(&ws[XOFF(q - 1) + (size_t)dd * DIM + cpan + c0]);
            add[0] += c[8 + q] * x.x; add[1] += c[8 + q] * x.y;
            add[2] += c[8 + q] * x.z; add[3] += c[8 + q] * x.w;
        }
        int col0 = cpan + c0;
        if (dd >= col0 && dd < col0 + 4) add[dd - col0] += c[8];
        float4 st = make_float4(acc[r][0] + add[0], acc[r][1] + add[1],
                                acc[r][2] + add[2], acc[r][3] + add[3]);
        *(float4*)&T[(size_t)dd * DIM + cpan + c0] = st;
    }
}

// ---- L3: E^i = X8 @ T_i + P0(i); i<64 -> Wf frags, i=64 -> G f32 ----------
__global__ __launch_bounds__(256) void k_ps2(float* __restrict__ ws)
{
    __shared__ __align__(16) float AT[DIM * 132];
    __shared__ __align__(16) float Bs[DIM * 36];
    int i = blockIdx.x + 1, cpan = blockIdx.y * 32, tid = threadIdx.x;
    float c[8]; c[0] = 1.0f;
    #pragma unroll
    for (int n = 1; n < 8; n++) c[n] = c[n - 1] * ((float)i / (float)n);
    stageA(ws + XOFF(7), AT, tid);
    const float* T = ws + TOFF(i);
    for (int idx = tid; idx < DIM * 32; idx += 256) {
        int k = idx >> 5, cc = idx & 31;
        Bs[k * 36 + cc] = T[(size_t)k * DIM + cpan + cc];
    }
    __syncthreads();
    float acc[4][4] = {};
    mm_core(AT, Bs, acc, tid);
    int d0 = (tid & 31) * 4, c0 = (tid >> 5) * 4;
    #pragma unroll
    for (int r = 0; r < 4; r++) {
        int dd = d0 + r;
        float add[4] = {0.f, 0.f, 0.f, 0.f};
        #pragma unroll
        for (int q = 1; q < 8; q++) {
            float4 x = ld4(&ws[XOFF(q - 1) + (size_t)dd * DIM + cpan + c0]);
            add[0] += c[q] * x.x; add[1] += c[q] * x.y;
            add[2] += c[q] * x.z; add[3] += c[q] * x.w;
        }
        int col0 = cpan + c0;
        if (dd >= col0 && dd < col0 + 4) add[dd - col0] += 1.0f;
        #pragma unroll
        for (int j = 0; j < 4; j++) acc[r][j] += add[j];
    }
    if (i == 64) {
        float* G = ws + GP(0);
        #pragma unroll
        for (int r = 0; r < 4; r++) {
            float4 st = make_float4(acc[r][0], acc[r][1], acc[r][2], acc[r][3]);
            *(float4*)&G[(size_t)(d0 + r) * DIM + cpan + c0] = st;
        }
        return;
    }
    __syncthreads();                      // Bs reads done -> reuse as Cs
    #pragma unroll
    for (int r = 0; r < 4; r++)
        #pragma unroll
        for (int j = 0; j < 4; j++) Bs[(d0 + r) * 36 + c0 + j] = acc[r][j];
    __syncthreads();
    _Float16* Wf = (_Float16*)(ws + FWOFFI);
    for (int ch = tid; ch < 512; ch += 256) {
        int m = ch >> 2, k0l = (ch & 3) * 8, k0 = cpan + k0l;
        f16x8 hv;
        #pragma unroll
        for (int q = 0; q < 8; q++) hv[q] = (_Float16)Bs[m * 36 + k0l + q];
        int lane = (m & 15) | (((k0 >> 3) & 3) << 4);
        size_t off = (size_t)i * 16384 + (((size_t)(m >> 4) * 4 + (k0 >> 5)) * 64 + lane) * 8;
        *(f16x8*)(Wf + off) = hv;
    }
}

// ---- L4: G^2..G^32 squarings + Y1..Y15 (1 WG) -----------------------------
__global__ __launch_bounds__(1024) void k_ylow(float* __restrict__ ws)
{
    __shared__ __align__(16) float AT[DIM * 132];
    __shared__ __align__(16) float Bs[DIM * 132];
    int tid = threadIdx.x;
    int d0 = (tid & 31) * 4, c0 = (tid >> 5) * 4;
    for (int e = tid; e < 16384; e += 1024) {
        float v = ws[GP(0) + e];
        AT[(e & 127) * 132 + (e >> 7)] = v;
        Bs[(e >> 7) * 132 + (e & 127)] = v;
    }
    __syncthreads();
    for (int s = 1; s <= 5; s++) {                        // G^(2^s)
        float acc[4][4] = {};
        #pragma unroll 4
        for (int k = 0; k < DIM; k++) {
            float4 a4 = ld4(&AT[k * 132 + d0]);
            float4 b4 = ld4(&Bs[k * 132 + c0]);
            float a_[4] = {a4.x, a4.y, a4.z, a4.w};
            float b_[4] = {b4.x, b4.y, b4.z, b4.w};
            #pragma unroll
            for (int i = 0; i < 4; i++)
                #pragma unroll
                for (int j = 0; j < 4; j++) acc[i][j] += a_[i] * b_[j];
        }
        __syncthreads();
        #pragma unroll
        for (int r = 0; r < 4; r++) {
            float4 st = make_float4(acc[r][0], acc[r][1], acc[r][2], acc[r][3]);
            *(float4*)&ws[GP(s) + (size_t)(d0 + r) * DIM + c0] = st;
            #pragma unroll
            for (int j = 0; j < 4; j++) {
                AT[(c0 + j) * 132 + (d0 + r)] = acc[r][j];
                Bs[(d0 + r) * 132 + (c0 + j)] = acc[r][j];
            }
        }
        __syncthreads();
    }
    // Y levels d=0..3 : Y_{2^d + j} = G^(2^d) * Y_j
    for (int d = 0; d < 4; d++) {
        for (int e = tid; e < 16384; e += 1024)
            AT[(e & 127) * 132 + (e >> 7)] = ws[GP(d) + e];
        __syncthreads();
        int nj = 1 << d;
        for (int jb = 0; jb < nj; jb += 2) {
            int npair = (nj - jb >= 2) ? 2 : 1;
            for (int e = tid; e < 8192 * npair; e += 1024) {
                int w = e >> 13, ee = e & 8191;
                Bs[(ee >> 6) * 132 + w * 64 + (ee & 63)] = ws[YOFFI + (size_t)(jb + w) * 8192 + ee];
            }
            __syncthreads();
            float acc[4][4] = {};
            if (c0 < npair * 64) {
                #pragma unroll 4
                for (int k = 0; k < DIM; k++) {
                    float4 a4 = ld4(&AT[k * 132 + d0]);
                    float4 b4 = ld4(&Bs[k * 132 + c0]);
                    float a_[4] = {a4.x, a4.y, a4.z, a4.w};
                    float b_[4] = {b4.x, b4.y, b4.z, b4.w};
                    #pragma unroll
                    for (int i = 0; i < 4; i++)
                        #pragma unroll
                        for (int j = 0; j < 4; j++) acc[i][j] += a_[i] * b_[j];
                }
                int jj = jb + (c0 >> 6), ccl = c0 & 63;
                int jout = (1 << d) + jj;
                #pragma unroll
                for (int r = 0; r < 4; r++) {
                    float4 st = make_float4(acc[r][0], acc[r][1], acc[r][2], acc[r][3]);
                    *(float4*)&ws[YOFFI + (size_t)jout * 8192 + (size_t)(d0 + r) * 64 + ccl] = st;
                }
            }
            __syncthreads();
        }
    }
}

// ---- L5/L6: Y_{jbase+jj} = G^(2^gslot) * Y_jj (+frags); optional conv WGs -
__global__ __launch_bounds__(256) void k_ylev(float* __restrict__ ws, int gslot,
                                              int jbase, int njobs,
                                              int nconvmats, int write_f32)
{
    __shared__ __align__(16) float AT[DIM * 132];
    __shared__ __align__(16) float Bs[DIM * 36];
    int bid = blockIdx.x, tid = threadIdx.x;
    int ncomp = njobs * 2;
    _Float16* Yf = (_Float16*)(ws + FYOFFI);
    if (bid < ncomp) {
        int jj = bid >> 1, bc = (bid & 1) * 32;
        int jout = jbase + jj;
        stageA(ws + GP(gslot), AT, tid);
        for (int idx = tid; idx < DIM * 32; idx += 256) {
            int k = idx >> 5, cc = idx & 31;
            Bs[k * 36 + cc] = ws[YOFFI + (size_t)jj * 8192 + (size_t)k * 64 + bc + cc];
        }
        __syncthreads();
        float acc[4][4] = {};
        mm_core(AT, Bs, acc, tid);
        int d0 = (tid & 31) * 4, c0 = (tid >> 5) * 4;
        __syncthreads();
        if (write_f32) {
            #pragma unroll
            for (int r = 0; r < 4; r++) {
                float4 st = make_float4(acc[r][0], acc[r][1], acc[r][2], acc[r][3]);
                *(float4*)&ws[YOFFI + (size_t)jout * 8192 + (size_t)(d0 + r) * 64 + bc + c0] = st;
            }
        }
        #pragma unroll
        for (int r = 0; r < 4; r++)
            #pragma unroll
            for (int j = 0; j < 4; j++) Bs[(d0 + r) * 36 + c0 + j] = acc[r][j];
        __syncthreads();
        for (int ch = tid; ch < 512; ch += 256) {
            int nloc = ch >> 4, k0 = (ch & 15) * 8;
            f16x8 hv;
            #pragma unroll
            for (int q = 0; q < 8; q++) hv[q] = (_Float16)Bs[(k0 + q) * 36 + nloc];
            int n = bc + nloc;
            int lane = (n & 15) | (((k0 >> 3) & 3) << 4);
            size_t off = (size_t)jout * 8192 + (((size_t)(n >> 4) * 4 + (k0 >> 5)) * 64 + lane) * 8;
            *(f16x8*)(Yf + off) = hv;
        }
    } else {
        int g = (bid - ncomp) * 256 + tid;
        if (g < nconvmats * 1024) {
            int j = g >> 10, cidx = g & 1023;
            int n = cidx >> 4, k0 = (cidx & 15) << 3;
            const float* src = ws + YOFFI + (size_t)j * 8192 + n;
            f16x8 hv;
            #pragma unroll
            for (int q = 0; q < 8; q++) hv[q] = (_Float16)src[(size_t)(k0 + q) * 64];
            int lane = (n & 15) | (((k0 >> 3) & 3) << 4);
            size_t off = (size_t)j * 8192 + (((size_t)(n >> 4) * 4 + (k0 >> 5)) * 64 + lane) * 8;
            *(f16x8*)(Yf + off) = hv;
        }
    }
}

// ---- L7: out[64j+i] = W_i @ Y_j via MFMA (batch-major nontemporal stores) -
__global__ __launch_bounds__(256) void k_final(const _Float16* __restrict__ Wf,
                                               const _Float16* __restrict__ Yf,
                                               float* __restrict__ out)
{
    int i = blockIdx.x, j = blockIdx.y;
    int tid = threadIdx.x, wave = tid >> 6, lane = tid & 63;
    const _Float16* Ab = Yf + (size_t)j * 8192;
    const _Float16* Bb = Wf + (size_t)i * 16384;
    f32x4 acc[4][2] = {};
    #pragma unroll
    for (int ks = 0; ks < 4; ks++) {
        f16x8 a[4], b[2];
        #pragma unroll
        for (int bt = 0; bt < 4; bt++)
            a[bt] = *(const f16x8*)(Ab + (((size_t)bt * 4 + ks) * 64 + lane) * 8);
        #pragma unroll
        for (int nn = 0; nn < 2; nn++)
            b[nn] = *(const f16x8*)(Bb + (((size_t)(wave * 2 + nn) * 4 + ks) * 64 + lane) * 8);
        #pragma unroll
        for (int bt = 0; bt < 4; bt++)
            #pragma unroll
            for (int nn = 0; nn < 2; nn++)
                acc[bt][nn] = __builtin_amdgcn_mfma_f32_16x16x32_f16(a[bt], b[nn], acc[bt][nn], 0, 0, 0);
    }
    float* slab = out + (size_t)(j * 64 + i) * 8192;
    int nlo = lane & 15, b0 = (lane >> 4) * 4;
    #pragma unroll
    for (int bt = 0; bt < 4; bt++)
        #pragma unroll
        for (int nn = 0; nn < 2; nn++) {
            int n = (wave * 2 + nn) * 16 + nlo;
            __builtin_nontemporal_store(acc[bt][nn],
                (f32x4*)&slab[(size_t)n * 64 + bt * 16 + b0]);
        }
}

extern "C" void kernel_launch(void* const* d_in, const int* in_sizes, int n_in,
                              void* d_out, int out_size, void* d_ws, size_t ws_size,
                              hipStream_t stream)
{
    const float* t  = (const float*)d_in[0];
    const float* x0 = (const float*)d_in[1];
    const float* S  = (const float*)d_in[2];
    const float* D  = (const float*)d_in[3];
    float* out = (float*)d_out;
    float* ws  = (float*)d_ws;
    _Float16* Wf = (_Float16*)(ws + FWOFFI);
    _Float16* Yf = (_Float16*)(ws + FYOFFI);

    hipLaunchKernelGGL(k_xpow, dim3(1), dim3(1024), 0, stream, t, x0, S, D, ws);
    hipLaunchKernelGGL(k_ps1,  dim3(64, 4), dim3(256), 0, stream, ws);
    hipLaunchKernelGGL(k_ps2,  dim3(64, 4), dim3(256), 0, stream, ws);
    hipLaunchKernelGGL(k_ylow, dim3(1), dim3(1024), 0, stream, ws);
    hipLaunchKernelGGL(k_ylev, dim3(32),  dim3(256), 0, stream, ws, 4, 16, 16, 0, 1);
    hipLaunchKernelGGL(k_ylev, dim3(128), dim3(256), 0, stream, ws, 5, 32, 32, 16, 0);
    hipLaunchKernelGGL(k_final, dim3(64, 64), dim3(256), 0, stream, Wf, Yf, out);
}

// Round 8
// 213.777 us; speedup vs baseline: 2.2328x; 1.7802x over previous
//
#include <hip/hip_runtime.h>
#include <math.h>

#define DIM 128
// ws float layout:
//   G^(2^s) f32, s=0..5 : GP(s) = s*16384        (GP(0) = E^64, from k_ps2)
//   Y[j] f32, j=0..63   : YOFFI + j*8192
//   X^q  (q=1..8)       : XOFF(q-1)
//   T_i  (i=1..64)      : TOFF(i)
//   Wf f16 frags        : float idx FWOFFI (64 mats x 16384 halves)
//   Yf f16 frags        : float idx FYOFFI (64 mats x 8192 halves)
#define GP(s)    ((s) * 16384)
#define YOFFI    (65 * 16384)
#define XOFF(q)  ((97 + (q)) * 16384)
#define TOFF(i)  ((105 + (i) - 1) * 16384)
#define FWOFFI   (169 * 16384)
#define FYOFFI   (201 * 16384)

typedef _Float16 f16x8 __attribute__((ext_vector_type(8)));
typedef float    f32x4 __attribute__((ext_vector_type(4)));

__device__ __forceinline__ float4 ld4(const float* p) { return *(const float4*)p; }

__device__ __forceinline__ void stageA(const float* __restrict__ A, float* AT, int tid)
{
    for (int idx = tid; idx < DIM * DIM; idx += 256)
        AT[(idx & 127) * 132 + (idx >> 7)] = A[idx];
}

__device__ __forceinline__ void mm_core(const float* AT, const float* Bs,
                                        float (&acc)[4][4], int tid)
{
    int d0 = (tid & 31) * 4, c0 = (tid >> 5) * 4;
    #pragma unroll 4
    for (int k = 0; k < DIM; k++) {
        float4 a4 = ld4(&AT[k * 132 + d0]);
        float4 b4 = ld4(&Bs[k * 36 + c0]);
        float a_[4] = {a4.x, a4.y, a4.z, a4.w};
        float b_[4] = {b4.x, b4.y, b4.z, b4.w};
        #pragma unroll
        for (int i = 0; i < 4; i++)
            #pragma unroll
            for (int j = 0; j < 4; j++) acc[i][j] += a_[i] * b_[j];
    }
}

__device__ __forceinline__ void mm_plain(const float* __restrict__ A,
                                         const float* __restrict__ B,
                                         float* __restrict__ C,
                                         int ncols, int cpan,
                                         float* AT, float* Bs, int tid)
{
    stageA(A, AT, tid);
    for (int idx = tid; idx < DIM * 32; idx += 256) {
        int k = idx >> 5, cc = idx & 31;
        Bs[k * 36 + cc] = B[(size_t)k * ncols + cpan + cc];
    }
    __syncthreads();
    float acc[4][4] = {};
    mm_core(AT, Bs, acc, tid);
    int d0 = (tid & 31) * 4, c0 = (tid >> 5) * 4;
    #pragma unroll
    for (int i = 0; i < 4; i++) {
        float4 st = make_float4(acc[i][0], acc[i][1], acc[i][2], acc[i][3]);
        *(float4*)&C[(size_t)(d0 + i) * ncols + cpan + c0] = st;
    }
}

// ---- L1: build X (per-WG redundant, in LDS), X^2 panel; Y0 + W0 frags -----
__global__ __launch_bounds__(256) void k_x2(const float* __restrict__ t,
                                            const float* __restrict__ x0,
                                            const float* __restrict__ S,
                                            const float* __restrict__ D,
                                            float* __restrict__ ws)
{
    __shared__ __align__(16) float AT[DIM * 132];
    __shared__ __align__(16) float Bs[DIM * 36];
    int tid = threadIdx.x, bid = blockIdx.x, cpan = bid * 32;
    float dt = t[1] - t[0];
    for (int e = tid; e < 16384; e += 256) {
        int r = e >> 7, c = e & 127;
        float a;
        if (r == c)      a = -log1pf(expf(D[r]));
        else if (r < c)  a =  S[(r * (2 * DIM - r - 1)) / 2 + (c - r - 1)];
        else             a = -S[(c * (2 * DIM - c - 1)) / 2 + (r - c - 1)];
        a *= dt;
        AT[c * 132 + r] = a;                         // AT[k][d] = X[d][k]
        if (c >= cpan && c < cpan + 32) Bs[r * 36 + (c - cpan)] = a;
        if (bid == 0) ws[XOFF(0) + e] = a;
    }
    if (bid == 1) for (int e = tid; e < 8192; e += 256) ws[YOFFI + e] = x0[e];
    if (bid == 2) {                                  // W0 = I fragments
        _Float16* Wf = (_Float16*)(ws + FWOFFI);
        for (int ch = tid; ch < 2048; ch += 256) {
            int m = ch >> 4, k0 = (ch & 15) << 3;
            f16x8 hv;
            #pragma unroll
            for (int q = 0; q < 8; q++) hv[q] = (m == k0 + q) ? (_Float16)1.0f : (_Float16)0.0f;
            int lane = (m & 15) | (((k0 >> 3) & 3) << 4);
            size_t off = (((size_t)(m >> 4) * 4 + (k0 >> 5)) * 64 + lane) * 8;
            *(f16x8*)(Wf + off) = hv;
        }
    }
    __syncthreads();
    float acc[4][4] = {};
    mm_core(AT, Bs, acc, tid);
    int d0 = (tid & 31) * 4, c0 = (tid >> 5) * 4;
    #pragma unroll
    for (int r = 0; r < 4; r++) {
        float4 st = make_float4(acc[r][0], acc[r][1], acc[r][2], acc[r][3]);
        *(float4*)&ws[XOFF(1) + (size_t)(d0 + r) * DIM + cpan + c0] = st;
    }
}

// ---- generic job matmul launch --------------------------------------------
struct Jobs { int4 jb[16]; };

__global__ __launch_bounds__(256) void k_lvl(float* __restrict__ ws, Jobs jobs)
{
    __shared__ __align__(16) float AT[DIM * 132];
    __shared__ __align__(16) float Bs[DIM * 36];
    int4 jb = jobs.jb[blockIdx.x];
    int ncols = jb.w;
    int cpan = blockIdx.y * 32;
    if (cpan >= ncols) return;
    mm_plain(ws + jb.x, ws + jb.y, ws + jb.z, ncols, cpan, AT, Bs, threadIdx.x);
}

// ---- L4: T_i = X8 @ P2(i) + P1(i), i=1..64 (grid 64x4) --------------------
__global__ __launch_bounds__(256) void k_ps1(float* __restrict__ ws)
{
    __shared__ __align__(16) float AT[DIM * 132];
    __shared__ __align__(16) float Bs[DIM * 36];
    int i = blockIdx.x + 1, cpan = blockIdx.y * 32, tid = threadIdx.x;
    float c[24]; c[0] = 1.0f;
    #pragma unroll
    for (int n = 1; n < 24; n++) c[n] = c[n - 1] * ((float)i / (float)n);
    stageA(ws + XOFF(7), AT, tid);
    for (int idx = tid; idx < DIM * 8; idx += 256) {
        int k = idx >> 3, cc4 = (idx & 7) * 4;
        float4 b = make_float4(0.f, 0.f, 0.f, 0.f);
        #pragma unroll
        for (int q = 1; q < 8; q++) {
            float4 x = ld4(&ws[XOFF(q - 1) + (size_t)k * DIM + cpan + cc4]);
            b.x += c[16 + q] * x.x; b.y += c[16 + q] * x.y;
            b.z += c[16 + q] * x.z; b.w += c[16 + q] * x.w;
        }
        int col = cpan + cc4;
        if (k >= col && k < col + 4) (&b.x)[k - col] += c[16];
        *(float4*)&Bs[k * 36 + cc4] = b;
    }
    __syncthreads();
    float acc[4][4] = {};
    mm_core(AT, Bs, acc, tid);
    int d0 = (tid & 31) * 4, c0 = (tid >> 5) * 4;
    float* T = ws + TOFF(i);
    #pragma unroll
    for (int r = 0; r < 4; r++) {
        int dd = d0 + r;
        float add[4] = {0.f, 0.f, 0.f, 0.f};
        #pragma unroll
        for (int q = 1; q < 8; q++) {
            float4 x = ld4(&ws[XOFF(q - 1) + (size_t)dd * DIM + cpan + c0]);
            add[0] += c[8 + q] * x.x; add[1] += c[8 + q] * x.y;
            add[2] += c[8 + q] * x.z; add[3] += c[8 + q] * x.w;
        }
        int col0 = cpan + c0;
        if (dd >= col0 && dd < col0 + 4) add[dd - col0] += c[8];
        float4 st = make_float4(acc[r][0] + add[0], acc[r][1] + add[1],
                                acc[r][2] + add[2], acc[r][3] + add[3]);
        *(float4*)&T[(size_t)dd * DIM + cpan + c0] = st;
    }
}

// ---- L5: E^i = X8 @ T_i + P0(i); i<64 -> Wf frags, i=64 -> G f32 ----------
__global__ __launch_bounds__(256) void k_ps2(float* __restrict__ ws)
{
    __shared__ __align__(16) float AT[DIM * 132];
    __shared__ __align__(16) float Bs[DIM * 36];
    int i = blockIdx.x + 1, cpan = blockIdx.y * 32, tid = threadIdx.x;
    float c[8]; c[0] = 1.0f;
    #pragma unroll
    for (int n = 1; n < 8; n++) c[n] = c[n - 1] * ((float)i / (float)n);
    stageA(ws + XOFF(7), AT, tid);
    const float* T = ws + TOFF(i);
    for (int idx = tid; idx < DIM * 32; idx += 256) {
        int k = idx >> 5, cc = idx & 31;
        Bs[k * 36 + cc] = T[(size_t)k * DIM + cpan + cc];
    }
    __syncthreads();
    float acc[4][4] = {};
    mm_core(AT, Bs, acc, tid);
    int d0 = (tid & 31) * 4, c0 = (tid >> 5) * 4;
    #pragma unroll
    for (int r = 0; r < 4; r++) {
        int dd = d0 + r;
        float add[4] = {0.f, 0.f, 0.f, 0.f};
        #pragma unroll
        for (int q = 1; q < 8; q++) {
            float4 x = ld4(&ws[XOFF(q - 1) + (size_t)dd * DIM + cpan + c0]);
            add[0] += c[q] * x.x; add[1] += c[q] * x.y;
            add[2] += c[q] * x.z; add[3] += c[q] * x.w;
        }
        int col0 = cpan + c0;
        if (dd >= col0 && dd < col0 + 4) add[dd - col0] += 1.0f;
        #pragma unroll
        for (int j = 0; j < 4; j++) acc[r][j] += add[j];
    }
    if (i == 64) {
        float* G = ws + GP(0);
        #pragma unroll
        for (int r = 0; r < 4; r++) {
            float4 st = make_float4(acc[r][0], acc[r][1], acc[r][2], acc[r][3]);
            *(float4*)&G[(size_t)(d0 + r) * DIM + cpan + c0] = st;
        }
        return;
    }
    __syncthreads();
    #pragma unroll
    for (int r = 0; r < 4; r++)
        #pragma unroll
        for (int j = 0; j < 4; j++) Bs[(d0 + r) * 36 + c0 + j] = acc[r][j];
    __syncthreads();
    _Float16* Wf = (_Float16*)(ws + FWOFFI);
    for (int ch = tid; ch < 512; ch += 256) {
        int m = ch >> 2, k0l = (ch & 3) * 8, k0 = cpan + k0l;
        f16x8 hv;
        #pragma unroll
        for (int q = 0; q < 8; q++) hv[q] = (_Float16)Bs[m * 36 + k0l + q];
        int lane = (m & 15) | (((k0 >> 3) & 3) << 4);
        size_t off = (size_t)i * 16384 + (((size_t)(m >> 4) * 4 + (k0 >> 5)) * 64 + lane) * 8;
        *(f16x8*)(Wf + off) = hv;
    }
}

// ---- Y level: Y products (+frags), optional conv WGs, optional G squaring -
__global__ __launch_bounds__(256) void k_ylev(float* __restrict__ ws, int gslot,
                                              int jbase, int njobs,
                                              int nconvmats, int write_f32,
                                              int sq_from, int sq_to)
{
    __shared__ __align__(16) float AT[DIM * 132];
    __shared__ __align__(16) float Bs[DIM * 36];
    int bid = blockIdx.x, tid = threadIdx.x;
    int ncomp = njobs * 2;
    int nconvw = nconvmats * 4;
    _Float16* Yf = (_Float16*)(ws + FYOFFI);
    if (bid < ncomp) {
        int jj = bid >> 1, bc = (bid & 1) * 32;
        int jout = jbase + jj;
        stageA(ws + GP(gslot), AT, tid);
        for (int idx = tid; idx < DIM * 32; idx += 256) {
            int k = idx >> 5, cc = idx & 31;
            Bs[k * 36 + cc] = ws[YOFFI + (size_t)jj * 8192 + (size_t)k * 64 + bc + cc];
        }
        __syncthreads();
        float acc[4][4] = {};
        mm_core(AT, Bs, acc, tid);
        int d0 = (tid & 31) * 4, c0 = (tid >> 5) * 4;
        __syncthreads();
        if (write_f32) {
            #pragma unroll
            for (int r = 0; r < 4; r++) {
                float4 st = make_float4(acc[r][0], acc[r][1], acc[r][2], acc[r][3]);
                *(float4*)&ws[YOFFI + (size_t)jout * 8192 + (size_t)(d0 + r) * 64 + bc + c0] = st;
            }
        }
        #pragma unroll
        for (int r = 0; r < 4; r++)
            #pragma unroll
            for (int j = 0; j < 4; j++) Bs[(d0 + r) * 36 + c0 + j] = acc[r][j];
        __syncthreads();
        for (int ch = tid; ch < 512; ch += 256) {
            int nloc = ch >> 4, k0 = (ch & 15) * 8;
            f16x8 hv;
            #pragma unroll
            for (int q = 0; q < 8; q++) hv[q] = (_Float16)Bs[(k0 + q) * 36 + nloc];
            int n = bc + nloc;
            int lane = (n & 15) | (((k0 >> 3) & 3) << 4);
            size_t off = (size_t)jout * 8192 + (((size_t)(n >> 4) * 4 + (k0 >> 5)) * 64 + lane) * 8;
            *(f16x8*)(Yf + off) = hv;
        }
    } else if (bid < ncomp + nconvw) {
        int g = (bid - ncomp) * 256 + tid;
        int j = g >> 10, cidx = g & 1023;
        int n = cidx >> 4, k0 = (cidx & 15) << 3;
        const float* src = ws + YOFFI + (size_t)j * 8192 + n;
        f16x8 hv;
        #pragma unroll
        for (int q = 0; q < 8; q++) hv[q] = (_Float16)src[(size_t)(k0 + q) * 64];
        int lane = (n & 15) | (((k0 >> 3) & 3) << 4);
        size_t off = (size_t)j * 8192 + (((size_t)(n >> 4) * 4 + (k0 >> 5)) * 64 + lane) * 8;
        *(f16x8*)(Yf + off) = hv;
    } else {
        int pan = (bid - ncomp - nconvw) * 32;
        mm_plain(ws + GP(sq_from), ws + GP(sq_from), ws + GP(sq_to), 128, pan, AT, Bs, tid);
    }
}

// ---- final: out[64j+i] = W_i @ Y_j via MFMA (batch-major stores) ----------
__global__ __launch_bounds__(256) void k_final(const _Float16* __restrict__ Wf,
                                               const _Float16* __restrict__ Yf,
                                               float* __restrict__ out)
{
    int i = blockIdx.x, j = blockIdx.y;
    int tid = threadIdx.x, wave = tid >> 6, lane = tid & 63;
    const _Float16* Ab = Yf + (size_t)j * 8192;
    const _Float16* Bb = Wf + (size_t)i * 16384;
    f32x4 acc[4][2] = {};
    #pragma unroll
    for (int ks = 0; ks < 4; ks++) {
        f16x8 a[4], b[2];
        #pragma unroll
        for (int bt = 0; bt < 4; bt++)
            a[bt] = *(const f16x8*)(Ab + (((size_t)bt * 4 + ks) * 64 + lane) * 8);
        #pragma unroll
        for (int nn = 0; nn < 2; nn++)
            b[nn] = *(const f16x8*)(Bb + (((size_t)(wave * 2 + nn) * 4 + ks) * 64 + lane) * 8);
        #pragma unroll
        for (int bt = 0; bt < 4; bt++)
            #pragma unroll
            for (int nn = 0; nn < 2; nn++)
                acc[bt][nn] = __builtin_amdgcn_mfma_f32_16x16x32_f16(a[bt], b[nn], acc[bt][nn], 0, 0, 0);
    }
    float* slab = out + (size_t)(j * 64 + i) * 8192;
    int nlo = lane & 15, b0 = (lane >> 4) * 4;
    #pragma unroll
    for (int bt = 0; bt < 4; bt++)
        #pragma unroll
        for (int nn = 0; nn < 2; nn++) {
            int n = (wave * 2 + nn) * 16 + nlo;
            __builtin_nontemporal_store(acc[bt][nn],
                (f32x4*)&slab[(size_t)n * 64 + bt * 16 + b0]);
        }
}

static inline void addjob(Jobs& J, int& n, int a, int b, int c, int nc)
{
    J.jb[n++] = make_int4(a, b, c, nc);
}

extern "C" void kernel_launch(void* const* d_in, const int* in_sizes, int n_in,
                              void* d_out, int out_size, void* d_ws, size_t ws_size,
                              hipStream_t stream)
{
    const float* t  = (const float*)d_in[0];
    const float* x0 = (const float*)d_in[1];
    const float* S  = (const float*)d_in[2];
    const float* D  = (const float*)d_in[3];
    float* out = (float*)d_out;
    float* ws  = (float*)d_ws;
    _Float16* Wf = (_Float16*)(ws + FWOFFI);
    _Float16* Yf = (_Float16*)(ws + FYOFFI);

    // L1: X, X^2 (+Y0, W0 frags)
    hipLaunchKernelGGL(k_x2, dim3(4), dim3(256), 0, stream, t, x0, S, D, ws);

    Jobs J; int n;
    // L2: X3 = X2*X ; X4 = X2*X2
    n = 0;
    addjob(J, n, XOFF(1), XOFF(0), XOFF(2), 128);
    addjob(J, n, XOFF(1), XOFF(1), XOFF(3), 128);
    hipLaunchKernelGGL(k_lvl, dim3(n, 4), dim3(256), 0, stream, ws, J);
    // L3: X5..X8 = X4 * X1..X4
    n = 0;
    for (int q = 1; q <= 4; q++) addjob(J, n, XOFF(3), XOFF(q - 1), XOFF(3 + q), 128);
    hipLaunchKernelGGL(k_lvl, dim3(n, 4), dim3(256), 0, stream, ws, J);

    // L4/L5: Paterson-Stockmeyer for E^1..E^64
    hipLaunchKernelGGL(k_ps1, dim3(64, 4), dim3(256), 0, stream, ws);
    hipLaunchKernelGGL(k_ps2, dim3(64, 4), dim3(256), 0, stream, ws);

    // G/Y levels 0..3 (f32, jobs): squaring + Y fills
    // d=0: G2 = G^2 ; Y1 = G Y0
    n = 0;
    addjob(J, n, GP(0), GP(0), GP(1), 128);
    addjob(J, n, GP(0), YOFFI, YOFFI + 8192, 64);
    hipLaunchKernelGGL(k_lvl, dim3(n, 4), dim3(256), 0, stream, ws, J);
    // d=1: G4 ; Y2,Y3
    n = 0;
    addjob(J, n, GP(1), GP(1), GP(2), 128);
    addjob(J, n, GP(1), YOFFI,        YOFFI + 2 * 8192, 64);
    addjob(J, n, GP(1), YOFFI + 8192, YOFFI + 3 * 8192, 64);
    hipLaunchKernelGGL(k_lvl, dim3(n, 4), dim3(256), 0, stream, ws, J);
    // d=2: G8 ; Y4..7
    n = 0;
    addjob(J, n, GP(2), GP(2), GP(3), 128);
    for (int jj = 0; jj < 4; jj++)
        addjob(J, n, GP(2), YOFFI + jj * 8192, YOFFI + (4 + jj) * 8192, 64);
    hipLaunchKernelGGL(k_lvl, dim3(n, 4), dim3(256), 0, stream, ws, J);
    // d=3: G16 ; Y8..15
    n = 0;
    addjob(J, n, GP(3), GP(3), GP(4), 128);
    for (int jj = 0; jj < 8; jj++)
        addjob(J, n, GP(3), YOFFI + jj * 8192, YOFFI + (8 + jj) * 8192, 64);
    hipLaunchKernelGGL(k_lvl, dim3(n, 4), dim3(256), 0, stream, ws, J);

    // d=4: Y16..31 (f32 + frags) ; G32 = G16^2 rides along (4 extra WGs)
    hipLaunchKernelGGL(k_ylev, dim3(36), dim3(256), 0, stream, ws, 4, 16, 16, 0, 1, 4, 5);
    // d=5: Y32..63 (frags only) + conv Y0..15 (64 WGs)
    hipLaunchKernelGGL(k_ylev, dim3(128), dim3(256), 0, stream, ws, 5, 32, 32, 16, 0, -1, -1);

    // out[64j+i] = W_i @ Y_j
    hipLaunchKernelGGL(k_final, dim3(64, 64), dim3(256), 0, stream, Wf, Yf, out);
}

// Round 9
// 201.667 us; speedup vs baseline: 2.3669x; 1.0600x over previous
//
#include <hip/hip_runtime.h>
#include <math.h>

#define DIM 128
// ws float layout:
//   G = E^64 f32 row-major : [0, 16384)
//   X^q (q=1..8)           : XOFF(q-1) = (97+q-1)*16384
//   T_i (i=1..64)          : TOFF(i)
//   Wf f16 frag tables     : float idx FWOFFI (64 mats x 16384 halves)
#define XOFF(q)  ((97 + (q)) * 16384)
#define TOFF(i)  ((105 + (i) - 1) * 16384)
#define FWOFFI   (169 * 16384)

typedef _Float16 f16x8 __attribute__((ext_vector_type(8)));
typedef float    f32x4 __attribute__((ext_vector_type(4)));

__device__ __forceinline__ float4 ld4(const float* p) { return *(const float4*)p; }

__device__ __forceinline__ void stageA(const float* __restrict__ A, float* AT, int tid)
{
    for (int idx = tid; idx < DIM * DIM; idx += 256)
        AT[(idx & 127) * 132 + (idx >> 7)] = A[idx];
}

__device__ __forceinline__ void mm_core(const float* AT, const float* Bs,
                                        float (&acc)[4][4], int tid)
{
    int d0 = (tid & 31) * 4, c0 = (tid >> 5) * 4;
    #pragma unroll 4
    for (int k = 0; k < DIM; k++) {
        float4 a4 = ld4(&AT[k * 132 + d0]);
        float4 b4 = ld4(&Bs[k * 36 + c0]);
        float a_[4] = {a4.x, a4.y, a4.z, a4.w};
        float b_[4] = {b4.x, b4.y, b4.z, b4.w};
        #pragma unroll
        for (int i = 0; i < 4; i++)
            #pragma unroll
            for (int j = 0; j < 4; j++) acc[i][j] += a_[i] * b_[j];
    }
}

// ---- L1: X (redundant per WG) + X^2..X^8 via per-panel recurrence ---------
// 4 WGs; WG b owns 32-col panel. X^q(:,p) = X @ X^{q-1}(:,p).
__global__ __launch_bounds__(256) void k_xall(const float* __restrict__ t,
                                              const float* __restrict__ S,
                                              const float* __restrict__ D,
                                              float* __restrict__ ws)
{
    __shared__ __align__(16) float AT[DIM * 132];
    __shared__ __align__(16) float Bs[DIM * 36];
    int tid = threadIdx.x, bid = blockIdx.x, cpan = bid * 32;
    float dt = t[1] - t[0];
    for (int e = tid; e < 16384; e += 256) {
        int r = e >> 7, c = e & 127;
        float a;
        if (r == c)      a = -log1pf(expf(D[r]));
        else if (r < c)  a =  S[(r * (2 * DIM - r - 1)) / 2 + (c - r - 1)];
        else             a = -S[(c * (2 * DIM - c - 1)) / 2 + (r - c - 1)];
        a *= dt;
        AT[c * 132 + r] = a;
        if (c >= cpan && c < cpan + 32) Bs[r * 36 + (c - cpan)] = a;
        if (bid == 0) ws[XOFF(0) + e] = a;
    }
    if (bid == 1) {                                  // W0 = I fragment table
        _Float16* Wf = (_Float16*)(ws + FWOFFI);
        for (int ch = tid; ch < 2048; ch += 256) {
            int m = ch >> 4, k0 = (ch & 15) << 3;
            f16x8 hv;
            #pragma unroll
            for (int q = 0; q < 8; q++) hv[q] = (m == k0 + q) ? (_Float16)1.0f : (_Float16)0.0f;
            int lane = (m & 15) | (((k0 >> 3) & 3) << 4);
            size_t off = (((size_t)(m >> 4) * 4 + (k0 >> 5)) * 64 + lane) * 8;
            *(f16x8*)(Wf + off) = hv;
        }
    }
    __syncthreads();
    int d0 = (tid & 31) * 4, c0 = (tid >> 5) * 4;
    for (int q = 2; q <= 8; q++) {
        float acc[4][4] = {};
        mm_core(AT, Bs, acc, tid);
        #pragma unroll
        for (int p = 0; p < 4; p++) {
            float4 st = make_float4(acc[p][0], acc[p][1], acc[p][2], acc[p][3]);
            *(float4*)&ws[XOFF(q - 1) + (size_t)(d0 + p) * DIM + cpan + c0] = st;
        }
        __syncthreads();
        #pragma unroll
        for (int p = 0; p < 4; p++)
            #pragma unroll
            for (int jj = 0; jj < 4; jj++) Bs[(d0 + p) * 36 + c0 + jj] = acc[p][jj];
        __syncthreads();
    }
}

// ---- L2: T_i = X8 @ P2(i) + P1(i), i=1..64 (grid 64x4) --------------------
__global__ __launch_bounds__(256) void k_ps1(float* __restrict__ ws)
{
    __shared__ __align__(16) float AT[DIM * 132];
    __shared__ __align__(16) float Bs[DIM * 36];
    int i = blockIdx.x + 1, cpan = blockIdx.y * 32, tid = threadIdx.x;
    float c[24]; c[0] = 1.0f;
    #pragma unroll
    for (int n = 1; n < 24; n++) c[n] = c[n - 1] * ((float)i / (float)n);
    stageA(ws + XOFF(7), AT, tid);
    for (int idx = tid; idx < DIM * 8; idx += 256) {
        int k = idx >> 3, cc4 = (idx & 7) * 4;
        float4 b = make_float4(0.f, 0.f, 0.f, 0.f);
        #pragma unroll
        for (int q = 1; q < 8; q++) {
            float4 x = ld4(&ws[XOFF(q - 1) + (size_t)k * DIM + cpan + cc4]);
            b.x += c[16 + q] * x.x; b.y += c[16 + q] * x.y;
            b.z += c[16 + q] * x.z; b.w += c[16 + q] * x.w;
        }
        int col = cpan + cc4;
        if (k >= col && k < col + 4) (&b.x)[k - col] += c[16];
        *(float4*)&Bs[k * 36 + cc4] = b;
    }
    __syncthreads();
    float acc[4][4] = {};
    mm_core(AT, Bs, acc, tid);
    int d0 = (tid & 31) * 4, c0 = (tid >> 5) * 4;
    float* T = ws + TOFF(i);
    #pragma unroll
    for (int r = 0; r < 4; r++) {
        int dd = d0 + r;
        float add[4] = {0.f, 0.f, 0.f, 0.f};
        #pragma unroll
        for (int q = 1; q < 8; q++) {
            float4 x = ld4(&ws[XOFF(q - 1) + (size_t)dd * DIM + cpan + c0]);
            add[0] += c[8 + q] * x.x; add[1] += c[8 + q] * x.y;
            add[2] += c[8 + q] * x.z; add[3] += c[8 + q] * x.w;
        }
        int col0 = cpan + c0;
        if (dd >= col0 && dd < col0 + 4) add[dd - col0] += c[8];
        float4 st = make_float4(acc[r][0] + add[0], acc[r][1] + add[1],
                                acc[r][2] + add[2], acc[r][3] + add[3]);
        *(float4*)&T[(size_t)dd * DIM + cpan + c0] = st;
    }
}

// ---- L3: E^i = X8 @ T_i + P0(i); i<64 -> Wf frags, i=64 -> G f32 ----------
__global__ __launch_bounds__(256) void k_ps2(float* __restrict__ ws)
{
    __shared__ __align__(16) float AT[DIM * 132];
    __shared__ __align__(16) float Bs[DIM * 36];
    int i = blockIdx.x + 1, cpan = blockIdx.y * 32, tid = threadIdx.x;
    float c[8]; c[0] = 1.0f;
    #pragma unroll
    for (int n = 1; n < 8; n++) c[n] = c[n - 1] * ((float)i / (float)n);
    stageA(ws + XOFF(7), AT, tid);
    const float* T = ws + TOFF(i);
    for (int idx = tid; idx < DIM * 32; idx += 256) {
        int k = idx >> 5, cc = idx & 31;
        Bs[k * 36 + cc] = T[(size_t)k * DIM + cpan + cc];
    }
    __syncthreads();
    float acc[4][4] = {};
    mm_core(AT, Bs, acc, tid);
    int d0 = (tid & 31) * 4, c0 = (tid >> 5) * 4;
    #pragma unroll
    for (int r = 0; r < 4; r++) {
        int dd = d0 + r;
        float add[4] = {0.f, 0.f, 0.f, 0.f};
        #pragma unroll
        for (int q = 1; q < 8; q++) {
            float4 x = ld4(&ws[XOFF(q - 1) + (size_t)dd * DIM + cpan + c0]);
            add[0] += c[q] * x.x; add[1] += c[q] * x.y;
            add[2] += c[q] * x.z; add[3] += c[q] * x.w;
        }
        int col0 = cpan + c0;
        if (dd >= col0 && dd < col0 + 4) add[dd - col0] += 1.0f;
        #pragma unroll
        for (int j = 0; j < 4; j++) acc[r][j] += add[j];
    }
    if (i == 64) {
        float* G = ws;
        #pragma unroll
        for (int r = 0; r < 4; r++) {
            float4 st = make_float4(acc[r][0], acc[r][1], acc[r][2], acc[r][3]);
            *(float4*)&G[(size_t)(d0 + r) * DIM + cpan + c0] = st;
        }
        return;
    }
    __syncthreads();
    #pragma unroll
    for (int r = 0; r < 4; r++)
        #pragma unroll
        for (int j = 0; j < 4; j++) Bs[(d0 + r) * 36 + c0 + j] = acc[r][j];
    __syncthreads();
    _Float16* Wf = (_Float16*)(ws + FWOFFI);
    for (int ch = tid; ch < 512; ch += 256) {
        int m = ch >> 2, k0l = (ch & 3) * 8, k0 = cpan + k0l;
        f16x8 hv;
        #pragma unroll
        for (int q = 0; q < 8; q++) hv[q] = (_Float16)Bs[m * 36 + k0l + q];
        int lane = (m & 15) | (((k0 >> 3) & 3) << 4);
        size_t off = (size_t)i * 16384 + (((size_t)(m >> 4) * 4 + (k0 >> 5)) * 64 + lane) * 8;
        *(f16x8*)(Wf + off) = hv;
    }
}

// ---- L4: fused tail. WG (j,q): MFMA hi/lo-split chain y = G^j x0 in LDS,
// then 16 output slabs out[64j + q*16+ii] = W_i @ Y_j (batch-major stores). -
__global__ __launch_bounds__(256, 1) void k_tail(const float* __restrict__ x0,
                                                 const float* __restrict__ ws,
                                                 float* __restrict__ out)
{
    __shared__ __align__(16) _Float16 fAhi[16384];
    __shared__ __align__(16) _Float16 fAlo[16384];
    __shared__ __align__(16) _Float16 fYhi[8192];
    __shared__ __align__(16) _Float16 fYlo[8192];
    const int j = blockIdx.x, q = blockIdx.y;
    const int tid = threadIdx.x, wave = tid >> 6, lane = tid & 63;
    const _Float16* Wf = (const _Float16*)(ws + FWOFFI);

    // init yfrag (b,k)-table holding y[k][b] = x0[k*64+b], hi/lo split
    #pragma unroll
    for (int r = 0; r < 4; r++) {
        int run = r * 256 + tid;
        int b = run >> 4, k0 = (run & 15) << 3;
        f16x8 h8, l8;
        #pragma unroll
        for (int qq = 0; qq < 8; qq++) {
            float v = x0[(size_t)(k0 + qq) * 64 + b];
            _Float16 h = (_Float16)v;
            h8[qq] = h; l8[qq] = (_Float16)(v - (float)h);
        }
        size_t off = ((size_t)((b >> 4) * 4 + (k0 >> 5)) * 64 + ((b & 15) | (((k0 >> 3) & 3) << 4))) * 8;
        *(f16x8*)(fYhi + off) = h8;
        *(f16x8*)(fYlo + off) = l8;
    }
    // init fragA (m,k)-table of P = G (f32 row-major at ws[0..16384))
    if (j > 0) {
        #pragma unroll
        for (int r = 0; r < 8; r++) {
            int run = r * 256 + tid;
            int m = run >> 4, k0 = (run & 15) << 3;
            const float* src = ws + (size_t)m * DIM + k0;
            f16x8 h8, l8;
            #pragma unroll
            for (int qq = 0; qq < 8; qq++) {
                float v = src[qq];
                _Float16 h = (_Float16)v;
                h8[qq] = h; l8[qq] = (_Float16)(v - (float)h);
            }
            size_t off = ((size_t)((m >> 4) * 4 + (k0 >> 5)) * 64 + ((m & 15) | (((k0 >> 3) & 3) << 4))) * 8;
            *(f16x8*)(fAhi + off) = h8;
            *(f16x8*)(fAlo + off) = l8;
        }
    }
    __syncthreads();

    const int RMt = (wave >> 1) * 4;     // row-tile base (4 tiles = 64 rows)
    const int CH  = (wave & 1);          // column half selector

    for (int s = 0; s < 6; s++) {
        bool domul = (j >> s) & 1;
        bool dosq  = (j >> (s + 1)) != 0;
        if (!domul && !dosq) break;
        f32x4 accy[4][2] = {};
        f32x4 acc[4][4] = {};
        for (int kc = 0; kc < 4; kc++) {
            f16x8 ah[4], al[4];
            #pragma unroll
            for (int mt = 0; mt < 4; mt++) {
                size_t ao = ((size_t)((RMt + mt) * 4 + kc) * 64 + lane) * 8;
                ah[mt] = *(const f16x8*)(fAhi + ao);
                al[mt] = *(const f16x8*)(fAlo + ao);
            }
            if (domul) {
                #pragma unroll
                for (int nn = 0; nn < 2; nn++) {
                    size_t bo = ((size_t)((CH * 2 + nn) * 4 + kc) * 64 + lane) * 8;
                    f16x8 bh = *(const f16x8*)(fYhi + bo);
                    f16x8 bl = *(const f16x8*)(fYlo + bo);
                    #pragma unroll
                    for (int mt = 0; mt < 4; mt++) {
                        accy[mt][nn] = __builtin_amdgcn_mfma_f32_16x16x32_f16(ah[mt], bh, accy[mt][nn], 0, 0, 0);
                        accy[mt][nn] = __builtin_amdgcn_mfma_f32_16x16x32_f16(ah[mt], bl, accy[mt][nn], 0, 0, 0);
                        accy[mt][nn] = __builtin_amdgcn_mfma_f32_16x16x32_f16(al[mt], bh, accy[mt][nn], 0, 0, 0);
                    }
                }
            }
            if (dosq) {
                int klo_hi = (lane >> 4) & 3;
                #pragma unroll
                for (int nt = 0; nt < 4; nt++) {
                    // b-frag B(k,n) = P[k][n] gathered by index from fragA
                    int n = CH * 64 + nt * 16 + (lane & 15);
                    int mt_b = kc * 2 + (klo_hi >> 1);
                    int lane_b = ((klo_hi & 1) << 3) | (((n >> 3) & 3) << 4);
                    size_t base = ((size_t)(mt_b * 4 + (n >> 5)) * 64 + lane_b) * 8 + (n & 7);
                    f16x8 bh, bl;
                    #pragma unroll
                    for (int qq = 0; qq < 8; qq++) {
                        bh[qq] = fAhi[base + (size_t)qq * 8];
                        bl[qq] = fAlo[base + (size_t)qq * 8];
                    }
                    #pragma unroll
                    for (int mt = 0; mt < 4; mt++) {
                        acc[mt][nt] = __builtin_amdgcn_mfma_f32_16x16x32_f16(ah[mt], bh, acc[mt][nt], 0, 0, 0);
                        acc[mt][nt] = __builtin_amdgcn_mfma_f32_16x16x32_f16(ah[mt], bl, acc[mt][nt], 0, 0, 0);
                        acc[mt][nt] = __builtin_amdgcn_mfma_f32_16x16x32_f16(al[mt], bh, acc[mt][nt], 0, 0, 0);
                    }
                }
            }
        }
        __syncthreads();
        if (domul) {
            #pragma unroll
            for (int mt = 0; mt < 4; mt++)
                #pragma unroll
                for (int nn = 0; nn < 2; nn++) {
                    int dbase = (RMt + mt) * 16 + ((lane >> 4) << 2);
                    int b = CH * 32 + nn * 16 + (lane & 15);
                    #pragma unroll
                    for (int p = 0; p < 4; p++) {
                        int d = dbase + p;
                        float v = accy[mt][nn][p];
                        _Float16 h = (_Float16)v;
                        size_t off = ((size_t)((b >> 4) * 4 + (d >> 5)) * 64 + ((b & 15) | (((d >> 3) & 3) << 4))) * 8 + (d & 7);
                        fYhi[off] = h;
                        fYlo[off] = (_Float16)(v - (float)h);
                    }
                }
        }
        if (dosq) {
            #pragma unroll
            for (int mt = 0; mt < 4; mt++)
                #pragma unroll
                for (int nt = 0; nt < 4; nt++) {
                    int rbase = (RMt + mt) * 16 + ((lane >> 4) << 2);
                    int c = CH * 64 + nt * 16 + (lane & 15);
                    #pragma unroll
                    for (int p = 0; p < 4; p++) {
                        int rr = rbase + p;
                        float v = acc[mt][nt][p];
                        _Float16 h = (_Float16)v;
                        size_t off = ((size_t)((rr >> 4) * 4 + (c >> 5)) * 64 + ((rr & 15) | (((c >> 3) & 3) << 4))) * 8 + (c & 7);
                        fAhi[off] = h;
                        fAlo[off] = (_Float16)(v - (float)h);
                    }
                }
        }
        __syncthreads();
    }

    // final: 16 slabs out[64j + i], i = q*16+ii; batch-major nontemporal
    f16x8 ya[4][4];
    #pragma unroll
    for (int bt = 0; bt < 4; bt++)
        #pragma unroll
        for (int ks = 0; ks < 4; ks++)
            ya[bt][ks] = *(const f16x8*)(fYhi + ((size_t)(bt * 4 + ks) * 64 + lane) * 8);
    int nlo = lane & 15, b0r = (lane >> 4) * 4;
    for (int ii = 0; ii < 16; ii++) {
        int i = q * 16 + ii;
        const _Float16* Wb = Wf + (size_t)i * 16384;
        f32x4 acc[4][2] = {};
        #pragma unroll
        for (int ks = 0; ks < 4; ks++) {
            f16x8 w0 = *(const f16x8*)(Wb + (((size_t)(wave * 2 + 0) * 4 + ks) * 64 + lane) * 8);
            f16x8 w1 = *(const f16x8*)(Wb + (((size_t)(wave * 2 + 1) * 4 + ks) * 64 + lane) * 8);
            #pragma unroll
            for (int bt = 0; bt < 4; bt++) {
                acc[bt][0] = __builtin_amdgcn_mfma_f32_16x16x32_f16(ya[bt][ks], w0, acc[bt][0], 0, 0, 0);
                acc[bt][1] = __builtin_amdgcn_mfma_f32_16x16x32_f16(ya[bt][ks], w1, acc[bt][1], 0, 0, 0);
            }
        }
        float* slab = out + (size_t)(j * 64 + i) * 8192;
        #pragma unroll
        for (int bt = 0; bt < 4; bt++)
            #pragma unroll
            for (int nn = 0; nn < 2; nn++) {
                int n = (wave * 2 + nn) * 16 + nlo;
                __builtin_nontemporal_store(acc[bt][nn],
                    (f32x4*)&slab[(size_t)n * 64 + bt * 16 + b0r]);
            }
    }
}

extern "C" void kernel_launch(void* const* d_in, const int* in_sizes, int n_in,
                              void* d_out, int out_size, void* d_ws, size_t ws_size,
                              hipStream_t stream)
{
    const float* t  = (const float*)d_in[0];
    const float* x0 = (const float*)d_in[1];
    const float* S  = (const float*)d_in[2];
    const float* D  = (const float*)d_in[3];
    float* out = (float*)d_out;
    float* ws  = (float*)d_ws;

    hipLaunchKernelGGL(k_xall, dim3(4), dim3(256), 0, stream, t, S, D, ws);
    hipLaunchKernelGGL(k_ps1,  dim3(64, 4), dim3(256), 0, stream, ws);
    hipLaunchKernelGGL(k_ps2,  dim3(64, 4), dim3(256), 0, stream, ws);
    hipLaunchKernelGGL(k_tail, dim3(64, 4), dim3(256), 0, stream, x0, ws, out);
}